// Round 6
// baseline (212.549 us; speedup 1.0000x reference)
//
#include <hip/hip_runtime.h>

// out = x + alpha * (x @ W^T).  M=8192, N=K=2048.
// R4 (2nd resubmit after infra timeouts): 256x256 8-phase barrier-pair GEMM
// (m201-style): BK=64, 8 waves (2Mx4N, per-wave 128x64 tile), double-buffered
// 4-quarter LDS (128KB), per-phase {ds_read || stage-quarter -> barrier ->
// lgkm0 -> 16 MFMA (setprio) -> barrier}, ONE counted vmcnt(4) per K-tile.
// Granule-XOR LDS swizzle. Epilogue: out = bf16(x) + alpha*acc, plain stores.
// Aux: memset -> prep(scatter+cvtX) -> cvtW -> gemm.

typedef unsigned short u16;
typedef __attribute__((ext_vector_type(8))) short bf16x8;
typedef __attribute__((ext_vector_type(4))) float f32x4;

#define HID 2048
#define BM 256
#define BN 256
#define BK 64
#define NT (HID / BK)          // 32 K-tiles
#define QSZ 8192               // u16 per quarter (128 rows x 64 cols)

__device__ __forceinline__ u16 f2bf(float f) {
    unsigned u = __builtin_bit_cast(unsigned, f);
    u += 0x7fffu + ((u >> 16) & 1u);   // RNE (finite normals)
    return (u16)(u >> 16);
}

__device__ __forceinline__ void cvt8(const float* __restrict__ src,
                                     u16* __restrict__ dst, int i) {
    const float4* p = (const float4*)src + (size_t)i * 2;
    float4 a = p[0], b = p[1];
    uint4 o;
    o.x = (unsigned)f2bf(a.x) | ((unsigned)f2bf(a.y) << 16);
    o.y = (unsigned)f2bf(a.z) | ((unsigned)f2bf(a.w) << 16);
    o.z = (unsigned)f2bf(b.x) | ((unsigned)f2bf(b.y) << 16);
    o.w = (unsigned)f2bf(b.z) | ((unsigned)f2bf(b.w) << 16);
    ((uint4*)dst)[i] = o;
}

__global__ void cvt_f32_bf16_kernel(const float* __restrict__ in,
                                    u16* __restrict__ out, int n8) {
    int stride = gridDim.x * blockDim.x;
    for (int i = blockIdx.x * blockDim.x + threadIdx.x; i < n8; i += stride)
        cvt8(in, out, i);
}

__global__ void scatter_coo_kernel(const int* __restrict__ idx,
                                   const float* __restrict__ vals,
                                   float* __restrict__ W, int nnz) {
    int n = blockIdx.x * blockDim.x + threadIdx.x;
    if (n < nnz)
        atomicAdd(W + (size_t)idx[n] * HID + idx[nnz + n], vals[n]);
}

// fused: COO scatter (gid < nnz) + x -> bf16 grid-stride convert
__global__ void prep_kernel(const int* __restrict__ idx,
                            const float* __restrict__ vals,
                            float* __restrict__ W, int nnz,
                            const float* __restrict__ x,
                            u16* __restrict__ xb, int n8x) {
    int gid = blockIdx.x * blockDim.x + threadIdx.x;
    if (gid < nnz)
        atomicAdd(W + (size_t)idx[gid] * HID + idx[nnz + gid], vals[gid]);
    int stride = gridDim.x * blockDim.x;
    for (int i = gid; i < n8x; i += stride)
        cvt8(x, xb, i);
}

#define GLDS(gsrc, ldst)                                                   \
    __builtin_amdgcn_global_load_lds(                                      \
        (const __attribute__((address_space(1))) void*)(gsrc),             \
        (__attribute__((address_space(3))) void*)(ldst), 16, 0, 0)

#define BAR()   __builtin_amdgcn_s_barrier()
#define SBAR()  __builtin_amdgcn_sched_barrier(0)
#define LGKM0() asm volatile("s_waitcnt lgkmcnt(0)" ::: "memory")

// C[m,n] = sum_k A[m,k]*B[n,k]; out = bf2f(A=Xb) + alpha*C.
__global__ __launch_bounds__(512, 2) void gemm8p_kernel(
        const u16* __restrict__ A,   // Xb [8192][2048] bf16
        const u16* __restrict__ B,   // Wb [2048][2048] bf16
        const float* __restrict__ alphap,
        float* __restrict__ out) {
    __shared__ u16 sh[8 * QSZ];      // 128 KB: buf{0,1} x {A0,A1,B0,B1}

    const int tid = threadIdx.x;
    const int lane = tid & 63;
    const int w = tid >> 6;          // wave 0..7
    const int wr = w >> 2;           // 0..1 : A-half (rows wr*128..)
    const int wc = w & 3;            // 0..3 : 64-col strip; B-half = wc>>1
    const int fr = lane & 15;
    const int kg = lane >> 4;
    const int xr = lane & 7;         // = fr & 7 (row&7 for fragment rows)

    // XCD swizzle: each XCD owns one bn column-panel (B panel L2-resident)
    const int bid = blockIdx.x;
    const int swz = (bid & 7) * 32 + (bid >> 3);   // 256 blocks, 32/XCD
    const int bm = swz & 31;
    const int bn = swz >> 5;
    const size_t rowBase = (size_t)bm * BM;
    const size_t colBase = (size_t)bn * BN;

    // ---- staging precompute: linear LDS dest, inverse-swizzled global src.
    // LDS quarter layout: elem = row*64 + (g ^ (row&7))*8, rows 0..127.
    // Sweep: thread tid covers row = half*64 + (tid>>3), phys granule tid&7,
    // so src granule = (tid&7) ^ ((tid>>3)&7).
    const int tb = tid >> 3;                       // 0..63
    const int g8 = ((tid & 7) ^ (tb & 7)) << 3;    // src elem offset in row
    const u16* aS = A + (rowBase + tb) * HID + g8;
    const u16* bS = B + (colBase + tb) * HID + g8;
    const int dst8 = tid * 8;

#define ST_A(buf, qa, tt) do {                                             \
    GLDS(aS + ((qa) * 128) * HID + (tt) * BK,                              \
         sh + (((buf) << 2) | (qa)) * QSZ + dst8);                         \
    GLDS(aS + ((qa) * 128 + 64) * HID + (tt) * BK,                         \
         sh + (((buf) << 2) | (qa)) * QSZ + 4096 + dst8);                  \
} while (0)
#define ST_B(buf, h, tt) do {                                              \
    GLDS(bS + ((h) * 128) * HID + (tt) * BK,                               \
         sh + (((buf) << 2) | (2 + (h))) * QSZ + dst8);                    \
    GLDS(bS + ((h) * 128 + 64) * HID + (tt) * BK,                          \
         sh + (((buf) << 2) | (2 + (h))) * QSZ + 4096 + dst8);             \
} while (0)

    // fragment-read granule offsets (elem) for k-sub 0 / 1
    const int gk0 = ((kg ^ xr)) << 3;
    const int gk1 = (((4 | kg) ^ xr)) << 3;

    f32x4 acc[8][4] = {};

    // ---- prologue: tile0 all quarters, tile1 B halves; fence vmcnt(4) ----
    ST_B(0, 0, 0); ST_B(0, 1, 0);
    ST_A(0, 0, 0); ST_A(0, 1, 0);
    ST_B(1, 0, 1); ST_B(1, 1, 1);
    asm volatile("s_waitcnt vmcnt(4)" ::: "memory");  // tile0 landed
    BAR(); SBAR();

#pragma unroll 1
    for (int t = 0; t < NT; ++t) {
        const int bufR = t & 1, bufW = bufR ^ 1;
        const u16* aq = sh + (((bufR << 2) | wr) * QSZ) + fr * 64;
        const u16* bq = sh + (((bufR << 2) | 2 | (wc >> 1)) * QSZ)
                           + ((wc & 1) << 12) + fr * 64;
        bf16x8 av[4], bv[4];

        // ===== P1: A(k0, m0-3) + B(k0); stage (t+1, A0) =====
#pragma unroll
        for (int m = 0; m < 4; ++m) av[m] = *(const bf16x8*)(aq + m * 1024 + gk0);
#pragma unroll
        for (int n = 0; n < 4; ++n) bv[n] = *(const bf16x8*)(bq + n * 1024 + gk0);
        if (t + 1 < NT) ST_A(bufW, 0, t + 1);
        BAR(); LGKM0(); SBAR();
        __builtin_amdgcn_s_setprio(1);
#pragma unroll
        for (int m = 0; m < 4; ++m)
#pragma unroll
            for (int n = 0; n < 4; ++n)
                acc[m][n] = __builtin_amdgcn_mfma_f32_16x16x32_bf16(
                    av[m], bv[n], acc[m][n], 0, 0, 0);
        __builtin_amdgcn_s_setprio(0);
        BAR(); SBAR();

        // ===== P2: A(k0, m4-7); reuse bv; stage (t+1, A1) =====
#pragma unroll
        for (int m = 0; m < 4; ++m) av[m] = *(const bf16x8*)(aq + (m + 4) * 1024 + gk0);
        if (t + 1 < NT) ST_A(bufW, 1, t + 1);
        BAR(); LGKM0(); SBAR();
        __builtin_amdgcn_s_setprio(1);
#pragma unroll
        for (int m = 0; m < 4; ++m)
#pragma unroll
            for (int n = 0; n < 4; ++n)
                acc[m + 4][n] = __builtin_amdgcn_mfma_f32_16x16x32_bf16(
                    av[m], bv[n], acc[m + 4][n], 0, 0, 0);
        __builtin_amdgcn_s_setprio(0);
        BAR(); SBAR();

        // ===== P3: A(k1, m0-3) + B(k1); no staging =====
#pragma unroll
        for (int m = 0; m < 4; ++m) av[m] = *(const bf16x8*)(aq + m * 1024 + gk1);
#pragma unroll
        for (int n = 0; n < 4; ++n) bv[n] = *(const bf16x8*)(bq + n * 1024 + gk1);
        BAR(); LGKM0(); SBAR();
        __builtin_amdgcn_s_setprio(1);
#pragma unroll
        for (int m = 0; m < 4; ++m)
#pragma unroll
            for (int n = 0; n < 4; ++n)
                acc[m][n] = __builtin_amdgcn_mfma_f32_16x16x32_bf16(
                    av[m], bv[n], acc[m][n], 0, 0, 0);
        __builtin_amdgcn_s_setprio(0);
        BAR(); SBAR();

        // ===== P4: A(k1, m4-7); stage (t+2, B0/B1) into bufR; fence =====
#pragma unroll
        for (int m = 0; m < 4; ++m) av[m] = *(const bf16x8*)(aq + (m + 4) * 1024 + gk1);
        if (t + 2 < NT) { ST_B(bufR, 0, t + 2); ST_B(bufR, 1, t + 2); }
        BAR(); LGKM0(); SBAR();
        __builtin_amdgcn_s_setprio(1);
#pragma unroll
        for (int m = 0; m < 4; ++m)
#pragma unroll
            for (int n = 0; n < 4; ++n)
                acc[m + 4][n] = __builtin_amdgcn_mfma_f32_16x16x32_bf16(
                    av[m], bv[n], acc[m + 4][n], 0, 0, 0);
        __builtin_amdgcn_s_setprio(0);
        // counted fence, once per K-tile: tile t+1 fully landed, 4 loads
        // (t+2 B halves) allowed in flight.
        if (t + 2 < NT)      asm volatile("s_waitcnt vmcnt(4)" ::: "memory");
        else if (t + 1 < NT) asm volatile("s_waitcnt vmcnt(0)" ::: "memory");
        BAR(); SBAR();
    }

    // ---- epilogue: out = bf16(x) + alpha*acc (plain stores) ----
    const float alphav = *alphap;
#pragma unroll
    for (int m = 0; m < 8; ++m) {
#pragma unroll
        for (int n = 0; n < 4; ++n) {
            f32x4 c = acc[m][n];
            const size_t gn = colBase + wc * 64 + n * 16 + fr;
#pragma unroll
            for (int j = 0; j < 4; ++j) {
                const size_t gm = rowBase + wr * 128 + m * 16 + kg * 4 + j;
                const size_t o = gm * HID + gn;
                unsigned xu = ((unsigned)A[o]) << 16;
                out[o] = __builtin_bit_cast(float, xu) + alphav * c[j];
            }
        }
    }
#undef ST_A
#undef ST_B
}

extern "C" void kernel_launch(void* const* d_in, const int* in_sizes, int n_in,
                              void* d_out, int out_size, void* d_ws, size_t ws_size,
                              hipStream_t stream) {
    const float* x     = (const float*)d_in[0];
    const int*   idx   = (const int*)d_in[1];
    const float* vals  = (const float*)d_in[2];
    const float* alpha = (const float*)d_in[3];
    float* out = (float*)d_out;

    const int nnz = in_sizes[2];
    const size_t MB = 1024 * 1024;
    const int n8W = (HID * HID) / 8;        // 524288
    const int n8X = in_sizes[0] / 8;        // 2097152
    const int grid = (8192 / BM) * (HID / BN);   // 256

    if (ws_size >= 56 * MB) {
        // disjoint: Xb [0,32M), Wb [32,40M), Wf [40,56M)
        u16*   Xb = (u16*)d_ws;
        u16*   Wb = (u16*)((char*)d_ws + 32 * MB);
        float* Wf = (float*)((char*)d_ws + 40 * MB);
        hipMemsetAsync(Wf, 0, (size_t)HID * HID * sizeof(float), stream);
        prep_kernel<<<2048, 256, 0, stream>>>(idx, vals, Wf, nnz, x, Xb, n8X);
        cvt_f32_bf16_kernel<<<2048, 256, 0, stream>>>(Wf, Wb, n8W);
        gemm8p_kernel<<<grid, 512, 0, stream>>>(Xb, Wb, alpha, out);
    } else {
        // fallback overlapping layout (W consumed before Xb written)
        float* Wf = (float*)d_ws;
        u16*   Xb = (u16*)d_ws;
        u16*   Wb = (u16*)((char*)d_ws + 32 * MB);
        hipMemsetAsync(Wf, 0, (size_t)HID * HID * sizeof(float), stream);
        scatter_coo_kernel<<<(nnz + 255) / 256, 256, 0, stream>>>(idx, vals, Wf, nnz);
        cvt_f32_bf16_kernel<<<2048, 256, 0, stream>>>(Wf, Wb, n8W);
        cvt_f32_bf16_kernel<<<2048, 256, 0, stream>>>(x, Xb, n8X);
        gemm8p_kernel<<<grid, 512, 0, stream>>>(Xb, Wb, alpha, out);
    }
}